// Round 2
// baseline (380.892 us; speedup 1.0000x reference)
//
#include <hip/hip_runtime.h>
#include <math.h>

// Problem constants (from reference setup_inputs)
#define BB   32
#define C0   512
#define HW0  1444   // 38*38  (== 4*361, so rows are 16B-aligned)
#define C1   1024
#define HW1  361    // 19*19  (odd -> rows not vector-alignable)
#define THRS 0.15f

#define CHUNKS0 12  // ceil(1444/128): 128 hw per block-chunk (float4 x 32 lanes)
#define CHUNKS1 12  // ceil(361/32):   32 hw per block-chunk (scalar x 32 lanes)

// ---------------------------------------------------------------------------
// K1: channel weights  w[b,c] = mean_{hw} g[b,c,hw]
// One 64-lane WAVE per row, 4 rows per 256-thread block. Level0 rows are
// 16B-aligned (5776B) -> float4; level1 rows (1444B) -> scalar.
// Shuffle-only reduction (no LDS, no barrier).
// Grid: 4096 level0 blocks (16384 rows) + 8192 level1 blocks (32768 rows).
// ---------------------------------------------------------------------------
__global__ void k_weights(const float* __restrict__ g0,
                          const float* __restrict__ g1,
                          float* __restrict__ w0,
                          float* __restrict__ w1) {
    int bid  = blockIdx.x;
    int tid  = threadIdx.x;
    int wv   = tid >> 6;       // wave id within block (0..3)
    int lane = tid & 63;
    float sum = 0.f;
    int level0 = (bid < 4096);
    int row;
    if (level0) {
        row = bid * 4 + wv;                       // 0..16383
        const float4* p4 = (const float4*)(g0 + (size_t)row * HW0);
        for (int i = lane; i < HW0 / 4; i += 64) {  // 361 float4s
            float4 v = p4[i];
            sum += (v.x + v.y) + (v.z + v.w);
        }
    } else {
        row = (bid - 4096) * 4 + wv;              // 0..32767
        const float* p = g1 + (size_t)row * HW1;
        for (int i = lane; i < HW1; i += 64) sum += p[i];
    }
    #pragma unroll
    for (int off = 32; off > 0; off >>= 1) sum += __shfl_down(sum, off, 64);
    if (lane == 0) {
        if (level0) w0[row] = sum * (1.0f / HW0);
        else        w1[row] = sum * (1.0f / HW1);
    }
}

// ---------------------------------------------------------------------------
// K2: single fused pass over Tf and Sf.
//   cam[b,hw]  = sum_c w[b,c]*Tf[b,c,hw]      -> ws scratch
//   outT[b,hw] = mean_c Tf[b,c,hw]            -> written straight into d_out
//   outS[b,hw] = mean_c Sf[b,c,hw]            -> written straight into d_out
// Block = 256 threads = 8 channel-groups x 32 hw-lanes; LDS tree reduce
// across groups. Level0: each lane owns 4 consecutive hw (float4 loads,
// 1KB per wave per instruction). Level1: scalar (odd row length).
// ---------------------------------------------------------------------------
__global__ void k_cam(const float* __restrict__ Tf0, const float* __restrict__ Sf0,
                      const float* __restrict__ Tf1, const float* __restrict__ Sf1,
                      const float* __restrict__ w0,  const float* __restrict__ w1,
                      float* __restrict__ cam0, float* __restrict__ cam1,
                      float* __restrict__ outT0, float* __restrict__ outS0,
                      float* __restrict__ outT1, float* __restrict__ outS1) {
    __shared__ float  wsh[C1];
    __shared__ float4 red[3][256];   // 12KB; level1 path uses .x only

    int bid = blockIdx.x;
    int tid = threadIdx.x;
    int cg = tid >> 5, lane = tid & 31;

    if (bid < BB * CHUNKS0) {
        // ---------------- level 0 (C=512, HW=1444), float4 path ----------------
        int b = bid / CHUNKS0, chunk = bid % CHUNKS0;
        for (int i = tid; i < C0; i += 256) wsh[i] = w0[b * C0 + i];
        __syncthreads();

        int hw = chunk * 128 + lane * 4;
        float4 camA = {0,0,0,0}, tA = {0,0,0,0}, sA = {0,0,0,0};
        if (hw < HW0) {
            size_t base = ((size_t)b * C0 + (size_t)cg * 64) * HW0 + hw;
            const float* pT = Tf0 + base;
            const float* pS = Sf0 + base;
            const float* pw = wsh + cg * 64;
            #pragma unroll 4
            for (int i = 0; i < 64; ++i) {
                float4 tv = *(const float4*)(pT + (size_t)i * HW0);
                float4 sv = *(const float4*)(pS + (size_t)i * HW0);
                float wc = pw[i];
                camA.x += wc * tv.x; camA.y += wc * tv.y;
                camA.z += wc * tv.z; camA.w += wc * tv.w;
                tA.x += tv.x; tA.y += tv.y; tA.z += tv.z; tA.w += tv.w;
                sA.x += sv.x; sA.y += sv.y; sA.z += sv.z; sA.w += sv.w;
            }
        }
        red[0][tid] = camA; red[1][tid] = tA; red[2][tid] = sA;
        __syncthreads();
        for (int s = 128; s >= 32; s >>= 1) {
            if (tid < s) {
                #pragma unroll
                for (int a = 0; a < 3; ++a) {
                    float4 x = red[a][tid], y = red[a][tid + s];
                    x.x += y.x; x.y += y.y; x.z += y.z; x.w += y.w;
                    red[a][tid] = x;
                }
            }
            __syncthreads();
        }
        if (tid < 32 && (chunk * 128 + tid * 4) < HW0) {
            size_t o = (size_t)b * HW0 + chunk * 128 + tid * 4;
            float4 c4 = red[0][tid], t4 = red[1][tid], s4 = red[2][tid];
            *(float4*)(cam0 + o) = c4;
            const float invC = 1.0f / C0;
            float2 tlo = {t4.x * invC, t4.y * invC}, thi = {t4.z * invC, t4.w * invC};
            float2 slo = {s4.x * invC, s4.y * invC}, shi = {s4.z * invC, s4.w * invC};
            *(float2*)(outT0 + o)     = tlo;  // d_out+2 is 8B-aligned, not 16B
            *(float2*)(outT0 + o + 2) = thi;
            *(float2*)(outS0 + o)     = slo;
            *(float2*)(outS0 + o + 2) = shi;
        }
    } else {
        // ---------------- level 1 (C=1024, HW=361), scalar path ----------------
        int id = bid - BB * CHUNKS0;
        int b = id / CHUNKS1, chunk = id % CHUNKS1;
        for (int i = tid; i < C1; i += 256) wsh[i] = w1[b * C1 + i];
        __syncthreads();

        int hw = chunk * 32 + lane;
        float camAcc = 0.f, tAcc = 0.f, sAcc = 0.f;
        if (hw < HW1) {
            size_t base = ((size_t)b * C1 + (size_t)cg * 128) * HW1 + hw;
            const float* pT = Tf1 + base;
            const float* pS = Sf1 + base;
            const float* pw = wsh + cg * 128;
            #pragma unroll 4
            for (int i = 0; i < 128; ++i) {
                float tv = pT[(size_t)i * HW1];
                float sv = pS[(size_t)i * HW1];
                camAcc += pw[i] * tv;
                tAcc   += tv;
                sAcc   += sv;
            }
        }
        red[0][tid].x = camAcc; red[1][tid].x = tAcc; red[2][tid].x = sAcc;
        __syncthreads();
        for (int s = 128; s >= 32; s >>= 1) {
            if (tid < s) {
                red[0][tid].x += red[0][tid + s].x;
                red[1][tid].x += red[1][tid + s].x;
                red[2][tid].x += red[2][tid + s].x;
            }
            __syncthreads();
        }
        if (tid < 32 && (chunk * 32 + tid) < HW1) {
            const float invC = 1.0f / C1;
            size_t o = (size_t)b * HW1 + chunk * 32 + tid;
            cam1[o]  = red[0][tid].x;
            outT1[o] = red[1][tid].x * invC;
            outS1[o] = red[2][tid].x * invC;
        }
    }
}

// ---------------------------------------------------------------------------
// K3: per-sample: raw-max of cam -> thresh; score = mean(relu(cam));
// zero emb entries where relu(cam) <= |thresh|. One block per (level, b).
// ---------------------------------------------------------------------------
__global__ void k_mask(const float* __restrict__ cam0, const float* __restrict__ cam1,
                       float* __restrict__ outT0, float* __restrict__ outS0,
                       float* __restrict__ outT1, float* __restrict__ outS1,
                       float* __restrict__ score) {
    int bid = blockIdx.x;
    const float* cam; float *outT, *outS, *sc; int HW, b;
    if (bid < BB) { cam = cam0; outT = outT0; outS = outS0; HW = HW0; b = bid;      sc = score; }
    else          { cam = cam1; outT = outT1; outS = outS1; HW = HW1; b = bid - BB; sc = score + BB; }
    int tid = threadIdx.x;
    const float* camb = cam + (size_t)b * HW;

    float m = -INFINITY, s = 0.f;
    for (int i = tid; i < HW; i += 256) {
        float c = camb[i];
        m = fmaxf(m, c);
        s += fmaxf(c, 0.f);
    }
    #pragma unroll
    for (int off = 32; off > 0; off >>= 1) {
        m = fmaxf(m, __shfl_down(m, off, 64));
        s += __shfl_down(s, off, 64);
    }
    __shared__ float rm[4], rs[4];
    __shared__ float bm;
    if ((tid & 63) == 0) { rm[tid >> 6] = m; rs[tid >> 6] = s; }
    __syncthreads();
    if (tid == 0) {
        float mm = fmaxf(fmaxf(rm[0], rm[1]), fmaxf(rm[2], rm[3]));
        float ss = (rs[0] + rs[1]) + (rs[2] + rs[3]);
        bm = mm;
        sc[b] = ss / (float)HW;
    }
    __syncthreads();
    float athr = fabsf(bm * THRS);
    float* oT = outT + (size_t)b * HW;
    float* oS = outS + (size_t)b * HW;
    for (int i = tid; i < HW; i += 256) {
        float c = fmaxf(camb[i], 0.f);
        if (!(c > athr)) { oT[i] = 0.f; oS[i] = 0.f; }
    }
}

// ---------------------------------------------------------------------------
// K4: fw = normalize([sum_b s0, sum_b s1])
// ---------------------------------------------------------------------------
__global__ void k_fw(const float* __restrict__ score, float* __restrict__ out) {
    int tid = threadIdx.x;   // 64 threads; score[0..31]=level0, [32..63]=level1
    float v = score[tid];
    #pragma unroll
    for (int off = 16; off > 0; off >>= 1) v += __shfl_down(v, off, 32);
    __shared__ float sh[2];
    if ((tid & 31) == 0) sh[tid >> 5] = v;
    __syncthreads();
    if (tid == 0) {
        float t = sh[0] + sh[1];
        out[0] = sh[0] / t;
        out[1] = sh[1] / t;
    }
}

// ---------------------------------------------------------------------------
extern "C" void kernel_launch(void* const* d_in, const int* in_sizes, int n_in,
                              void* d_out, int out_size, void* d_ws, size_t ws_size,
                              hipStream_t stream) {
    const float* Tf0 = (const float*)d_in[0];
    const float* Tf1 = (const float*)d_in[1];
    const float* Sf0 = (const float*)d_in[2];
    const float* Sf1 = (const float*)d_in[3];
    const float* g0  = (const float*)d_in[4];
    const float* g1  = (const float*)d_in[5];

    float* out   = (float*)d_out;
    float* fw    = out;                    // [2]
    float* outT0 = out + 2;                // [B, HW0]
    float* outT1 = outT0 + BB * HW0;       // [B, HW1]
    float* outS0 = outT1 + BB * HW1;       // [B, HW0]
    float* outS1 = outS0 + BB * HW0;       // [B, HW1]

    // scratch: w0(16384) w1(32768) cam0(46208) cam1(11552) score(64)
    //          = ~428 KB
    float* ws    = (float*)d_ws;
    float* w0    = ws;
    float* w1    = w0 + BB * C0;
    float* cam0  = w1 + BB * C1;
    float* cam1  = cam0 + BB * HW0;
    float* score = cam1 + BB * HW1;

    k_weights<<<4096 + 8192, 256, 0, stream>>>(g0, g1, w0, w1);
    k_cam<<<BB * CHUNKS0 + BB * CHUNKS1, 256, 0, stream>>>(
        Tf0, Sf0, Tf1, Sf1, w0, w1, cam0, cam1, outT0, outS0, outT1, outS1);
    k_mask<<<2 * BB, 256, 0, stream>>>(cam0, cam1, outT0, outS0, outT1, outS1, score);
    k_fw<<<1, 64, 0, stream>>>(score, fw);
}

// Round 7
// 379.081 us; speedup vs baseline: 1.0048x; 1.0048x over previous
//
#include <hip/hip_runtime.h>
#include <math.h>

// Problem constants (from reference setup_inputs)
#define BB   32
#define C0   512
#define HW0  1444   // 38*38  (== 4*361, rows 16B-aligned)
#define C1   1024
#define HW1  361    // 19*19  (odd -> scalar loads)
#define THRS 0.15f

#define CHUNKS0 12  // ceil(1444/128): 128 hw per chunk (float4 x 32 lanes)
#define CHUNKS1 12  // ceil(361/32):   32 hw per chunk  (scalar x 32 lanes)
#define SPLIT   4   // channel-dim split per (b,chunk) -> 4x blocks for occupancy

// ---------------------------------------------------------------------------
// K1: channel weights  w[b,c] = mean_{hw} g[b,c,hw]
// One 64-lane wave per row, 4 rows per block. 49152 waves -> saturated.
// ---------------------------------------------------------------------------
__global__ void k_weights(const float* __restrict__ g0,
                          const float* __restrict__ g1,
                          float* __restrict__ w0,
                          float* __restrict__ w1) {
    int bid  = blockIdx.x;
    int tid  = threadIdx.x;
    int wv   = tid >> 6;
    int lane = tid & 63;
    float sum = 0.f;
    int level0 = (bid < 4096);
    int row;
    if (level0) {
        row = bid * 4 + wv;                       // 0..16383
        const float4* p4 = (const float4*)(g0 + (size_t)row * HW0);
        for (int i = lane; i < HW0 / 4; i += 64) {
            float4 v = p4[i];
            sum += (v.x + v.y) + (v.z + v.w);
        }
    } else {
        row = (bid - 4096) * 4 + wv;              // 0..32767
        const float* p = g1 + (size_t)row * HW1;
        for (int i = lane; i < HW1; i += 64) sum += p[i];
    }
    #pragma unroll
    for (int off = 32; off > 0; off >>= 1) sum += __shfl_down(sum, off, 64);
    if (lane == 0) {
        if (level0) w0[row] = sum * (1.0f / HW0);
        else        w1[row] = sum * (1.0f / HW1);
    }
}

// ---------------------------------------------------------------------------
// K2: fused partial pass over Tf and Sf, channel-split 4x.
// Each block: one (level, b, hw-chunk, channel-part). Partials to scratch:
//   camP[part][b][hw] = sum_{c in part} w*Tf ; tP = sum Tf ; sP = sum Sf
// Block = 256 threads = 8 cgroups x 32 lanes; LDS tree reduce across groups.
// Grid 3072 blocks x 4 waves = 12288 waves -> ~full occupancy demand.
// ---------------------------------------------------------------------------
__global__ void k_cam(const float* __restrict__ Tf0, const float* __restrict__ Sf0,
                      const float* __restrict__ Tf1, const float* __restrict__ Sf1,
                      const float* __restrict__ w0,  const float* __restrict__ w1,
                      float* __restrict__ camP0, float* __restrict__ tP0, float* __restrict__ sP0,
                      float* __restrict__ camP1, float* __restrict__ tP1, float* __restrict__ sP1) {
    __shared__ float  wsh[256];
    __shared__ float4 red[3][256];   // 12KB; level1 uses .x only

    int bid = blockIdx.x;
    int tid = threadIdx.x;
    int cg = tid >> 5, lane = tid & 31;

    if (bid < BB * CHUNKS0 * SPLIT) {
        // ------------- level 0 (C=512, HW=1444), float4, 128 ch/part -------------
        int b = bid / (CHUNKS0 * SPLIT);
        int rem = bid % (CHUNKS0 * SPLIT);
        int chunk = rem >> 2, part = rem & 3;
        if (tid < 128) wsh[tid] = w0[b * C0 + part * 128 + tid];
        __syncthreads();

        int hw = chunk * 128 + lane * 4;
        float4 camA = {0,0,0,0}, tA = {0,0,0,0}, sA = {0,0,0,0};
        if (hw < HW0) {
            // channels: part*128 + cg*16 .. +16
            size_t base = ((size_t)b * C0 + (size_t)part * 128 + (size_t)cg * 16) * HW0 + hw;
            const float* pT = Tf0 + base;
            const float* pS = Sf0 + base;
            const float* pw = wsh + cg * 16;
            #pragma unroll
            for (int i = 0; i < 16; ++i) {
                float4 tv = *(const float4*)(pT + (size_t)i * HW0);
                float4 sv = *(const float4*)(pS + (size_t)i * HW0);
                float wc = pw[i];
                camA.x += wc * tv.x; camA.y += wc * tv.y;
                camA.z += wc * tv.z; camA.w += wc * tv.w;
                tA.x += tv.x; tA.y += tv.y; tA.z += tv.z; tA.w += tv.w;
                sA.x += sv.x; sA.y += sv.y; sA.z += sv.z; sA.w += sv.w;
            }
        }
        red[0][tid] = camA; red[1][tid] = tA; red[2][tid] = sA;
        __syncthreads();
        for (int s = 128; s >= 32; s >>= 1) {
            if (tid < s) {
                #pragma unroll
                for (int a = 0; a < 3; ++a) {
                    float4 x = red[a][tid], y = red[a][tid + s];
                    x.x += y.x; x.y += y.y; x.z += y.z; x.w += y.w;
                    red[a][tid] = x;
                }
            }
            __syncthreads();
        }
        if (tid < 32 && (chunk * 128 + tid * 4) < HW0) {
            size_t o = ((size_t)part * BB + b) * HW0 + chunk * 128 + tid * 4;
            *(float4*)(camP0 + o) = red[0][tid];
            *(float4*)(tP0   + o) = red[1][tid];
            *(float4*)(sP0   + o) = red[2][tid];
        }
    } else {
        // ------------- level 1 (C=1024, HW=361), scalar, 256 ch/part -------------
        int id = bid - BB * CHUNKS0 * SPLIT;
        int b = id / (CHUNKS1 * SPLIT);
        int rem = id % (CHUNKS1 * SPLIT);
        int chunk = rem >> 2, part = rem & 3;
        wsh[tid] = w1[b * C1 + part * 256 + tid];
        __syncthreads();

        int hw = chunk * 32 + lane;
        float camAcc = 0.f, tAcc = 0.f, sAcc = 0.f;
        if (hw < HW1) {
            // channels: part*256 + cg*32 .. +32
            size_t base = ((size_t)b * C1 + (size_t)part * 256 + (size_t)cg * 32) * HW1 + hw;
            const float* pT = Tf1 + base;
            const float* pS = Sf1 + base;
            const float* pw = wsh + cg * 32;
            #pragma unroll 8
            for (int i = 0; i < 32; ++i) {
                float tv = pT[(size_t)i * HW1];
                float sv = pS[(size_t)i * HW1];
                camAcc += pw[i] * tv;
                tAcc   += tv;
                sAcc   += sv;
            }
        }
        red[0][tid].x = camAcc; red[1][tid].x = tAcc; red[2][tid].x = sAcc;
        __syncthreads();
        for (int s = 128; s >= 32; s >>= 1) {
            if (tid < s) {
                red[0][tid].x += red[0][tid + s].x;
                red[1][tid].x += red[1][tid + s].x;
                red[2][tid].x += red[2][tid + s].x;
            }
            __syncthreads();
        }
        if (tid < 32 && (chunk * 32 + tid) < HW1) {
            size_t o = ((size_t)part * BB + b) * HW1 + chunk * 32 + tid;
            camP1[o] = red[0][tid].x;
            tP1[o]   = red[1][tid].x;
            sP1[o]   = red[2][tid].x;
        }
    }
}

// ---------------------------------------------------------------------------
// K3: per-(level,b): combine the 4 channel-partials in LDS, compute raw-max
// -> thresh and score = mean(relu(cam)), then write masked embeddings.
// ---------------------------------------------------------------------------
__global__ void k_mask(const float* __restrict__ camP0, const float* __restrict__ tP0,
                       const float* __restrict__ sP0,
                       const float* __restrict__ camP1, const float* __restrict__ tP1,
                       const float* __restrict__ sP1,
                       float* __restrict__ outT0, float* __restrict__ outS0,
                       float* __restrict__ outT1, float* __restrict__ outS1,
                       float* __restrict__ score) {
    __shared__ float camL[HW0], tL[HW0], sL[HW0];   // 17.3KB
    __shared__ float rm[4], rs[4], bm;

    int bid = blockIdx.x;
    int tid = threadIdx.x;
    const float *camP, *tP, *sP; float *outT, *outS, *sc;
    int HW, b; float invC;
    if (bid < BB) {
        camP = camP0; tP = tP0; sP = sP0; outT = outT0; outS = outS0;
        HW = HW0; b = bid; sc = score; invC = 1.0f / C0;
    } else {
        camP = camP1; tP = tP1; sP = sP1; outT = outT1; outS = outS1;
        HW = HW1; b = bid - BB; sc = score + BB; invC = 1.0f / C1;
    }
    size_t strideP = (size_t)BB * HW;
    size_t base = (size_t)b * HW;

    float m = -INFINITY, s = 0.f;
    for (int i = tid; i < HW; i += 256) {
        float c = camP[base + i] + camP[strideP + base + i]
                + camP[2 * strideP + base + i] + camP[3 * strideP + base + i];
        float t = tP[base + i] + tP[strideP + base + i]
                + tP[2 * strideP + base + i] + tP[3 * strideP + base + i];
        float v = sP[base + i] + sP[strideP + base + i]
                + sP[2 * strideP + base + i] + sP[3 * strideP + base + i];
        camL[i] = c; tL[i] = t; sL[i] = v;
        m = fmaxf(m, c);
        s += fmaxf(c, 0.f);
    }
    #pragma unroll
    for (int off = 32; off > 0; off >>= 1) {
        m = fmaxf(m, __shfl_down(m, off, 64));
        s += __shfl_down(s, off, 64);
    }
    if ((tid & 63) == 0) { rm[tid >> 6] = m; rs[tid >> 6] = s; }
    __syncthreads();
    if (tid == 0) {
        float mm = fmaxf(fmaxf(rm[0], rm[1]), fmaxf(rm[2], rm[3]));
        float ss = (rs[0] + rs[1]) + (rs[2] + rs[3]);
        bm = mm;
        sc[b] = ss / (float)HW;
    }
    __syncthreads();
    float athr = fabsf(bm * THRS);
    for (int i = tid; i < HW; i += 256) {
        float c = fmaxf(camL[i], 0.f);
        bool keep = (c > athr);
        outT[base + i] = keep ? tL[i] * invC : 0.f;
        outS[base + i] = keep ? sL[i] * invC : 0.f;
    }
}

// ---------------------------------------------------------------------------
// K4: fw = normalize([sum_b s0, sum_b s1])
// ---------------------------------------------------------------------------
__global__ void k_fw(const float* __restrict__ score, float* __restrict__ out) {
    int tid = threadIdx.x;   // 64 threads; score[0..31]=level0, [32..63]=level1
    float v = score[tid];
    #pragma unroll
    for (int off = 16; off > 0; off >>= 1) v += __shfl_down(v, off, 32);
    __shared__ float sh[2];
    if ((tid & 31) == 0) sh[tid >> 5] = v;
    __syncthreads();
    if (tid == 0) {
        float t = sh[0] + sh[1];
        out[0] = sh[0] / t;
        out[1] = sh[1] / t;
    }
}

// ---------------------------------------------------------------------------
extern "C" void kernel_launch(void* const* d_in, const int* in_sizes, int n_in,
                              void* d_out, int out_size, void* d_ws, size_t ws_size,
                              hipStream_t stream) {
    const float* Tf0 = (const float*)d_in[0];
    const float* Tf1 = (const float*)d_in[1];
    const float* Sf0 = (const float*)d_in[2];
    const float* Sf1 = (const float*)d_in[3];
    const float* g0  = (const float*)d_in[4];
    const float* g1  = (const float*)d_in[5];

    float* out   = (float*)d_out;
    float* fw    = out;                    // [2]
    float* outT0 = out + 2;                // [B, HW0]
    float* outT1 = outT0 + BB * HW0;       // [B, HW1]
    float* outS0 = outT1 + BB * HW1;       // [B, HW0]
    float* outS1 = outS0 + BB * HW0;       // [B, HW1]

    // scratch layout (floats): ~2.97 MB total
    float* ws    = (float*)d_ws;
    float* w0    = ws;                       // 16384
    float* w1    = w0 + BB * C0;             // 32768
    float* camP0 = w1 + BB * C1;             // 4*46208
    float* tP0   = camP0 + SPLIT * BB * HW0;
    float* sP0   = tP0   + SPLIT * BB * HW0;
    float* camP1 = sP0   + SPLIT * BB * HW0; // 4*11552
    float* tP1   = camP1 + SPLIT * BB * HW1;
    float* sP1   = tP1   + SPLIT * BB * HW1;
    float* score = sP1   + SPLIT * BB * HW1; // 64

    k_weights<<<4096 + 8192, 256, 0, stream>>>(g0, g1, w0, w1);
    k_cam<<<BB * CHUNKS0 * SPLIT + BB * CHUNKS1 * SPLIT, 256, 0, stream>>>(
        Tf0, Sf0, Tf1, Sf1, w0, w1, camP0, tP0, sP0, camP1, tP1, sP1);
    k_mask<<<2 * BB, 256, 0, stream>>>(camP0, tP0, sP0, camP1, tP1, sP1,
                                       outT0, outS0, outT1, outS1, score);
    k_fw<<<1, 64, 0, stream>>>(score, fw);
}